// Round 2
// baseline (418.256 us; speedup 1.0000x reference)
//
#include <hip/hip_runtime.h>

// LiftSplatBEV: B=2, N=6, C=64, HF=112, WF=200, D=64, BEV 200x200
#define BB   2
#define NN   6
#define CCH  64
#define HFE  112
#define WFE  200
#define DDE  64
#define HWF  (HFE*WFE)      // 22400 feature pixels (= 350*64); /4 = 5600 float4 groups
#define HWF4 (HWF/4)
#define BEVH 200
#define BEVW 200
#define HWB  (BEVH*BEVW)    // 40000 BEV cells
#define NBINS (BB*HWB)      // 80000 (b,cell) bins
#define NBINS_PAD 81920     // 320*256
#define NSCANB (NBINS_PAD/256)  // 320
#define MAXENT (BB*NN*HWF*4)    // 1,075,200 max entries (4 per valid slot)
#define NCHUNK (MAXENT/64)      // 16800 64-entry chunks
#define ACC_ELEMS ((size_t)BB*HWB*CCH)   // channel-last [b*HWB+cell][c]

__device__ __forceinline__ float4 f4max(float4 a, float4 b) {
    return make_float4(fmaxf(a.x,b.x), fmaxf(a.y,b.y), fmaxf(a.z,b.z), fmaxf(a.w,b.w));
}

// ---------------- shared geometry (bug-faithful to reference) ----------------
struct Geo {
    int valid;
    int c00, c10, c01, c11;
    float w00, w10, w01, w11;
};

__device__ __forceinline__ Geo geo_compute(int bn, int p,
    const float* __restrict__ I_inv, const float* __restrict__ E_inv,
    const float* __restrict__ Vm)
{
    Geo g; g.valid = 0;
    // bug-faithful w-outer flatten: u = p/112, v = p%112
    const float u = (float)(p / HFE);
    const float v = (float)(p % HFE);
    const float* Ii = I_inv + bn * 9;
    const float* Ei = E_inv + bn * 16;
    float cx = Ii[0]*u + Ii[1]*v + Ii[2];
    float cy = Ii[3]*u + Ii[4]*v + Ii[5];
    float cz = Ii[6]*u + Ii[7]*v + Ii[8];
    float tx = Ei[3], ty = Ei[7], tz = Ei[11];
    float dx = Ei[0]*cx + Ei[1]*cy + Ei[2] *cz + tx;   // includes translation (bug-faithful)
    float dy = Ei[4]*cx + Ei[5]*cy + Ei[6] *cz + ty;
    float dz = Ei[8]*cx + Ei[9]*cy + Ei[10]*cz + tz;
    float s  = -tz / fmaxf(dz, 1e-6f);
    float ex = tx + dx * s;
    float ey = ty + dy * s;
    float prx = Vm[0]*ex + Vm[1]*ey + Vm[2];
    float pry = Vm[3]*ex + Vm[4]*ey + Vm[5];
    float prz = Vm[6]*ex + Vm[7]*ey + Vm[8];
    float den = fmaxf(prz, 1e-7f);
    float bx = prx / den, by = pry / den;
    // bug-faithful gx->px roundtrip, same association order as reference
    float gx = bx / (float)(BEVW-1) * 2.0f - 1.0f;
    float gy = by / (float)(BEVH-1) * 2.0f - 1.0f;
    float px = (gx + 1.0f) * (float)(BEVW-1) / 2.0f;
    float py = (gy + 1.0f) * (float)(BEVH-1) / 2.0f;
    float x0f = fminf(fmaxf(floorf(px), 0.0f), (float)(BEVW-1));
    float y0f = fminf(fmaxf(floorf(py), 0.0f), (float)(BEVH-1));
    float x1f = fminf(x0f + 1.0f, (float)(BEVW-1));
    float y1f = fminf(y0f + 1.0f, (float)(BEVH-1));
    // far-edge-degenerate slots cancel exactly in the fp64 np reference: skip
    if (x0f == x1f || y0f == y1f) return g;
    float wx0 = x1f - px, wx1 = px - x0f;
    float wy0 = y1f - py, wy1 = py - y0f;
    int x0 = (int)x0f, x1 = (int)x1f, y0 = (int)y0f, y1 = (int)y1f;
    g.c00 = y0*BEVW + x0;  g.w00 = wx0*wy0;
    g.c10 = y0*BEVW + x1;  g.w10 = wx1*wy0;
    g.c01 = y1*BEVW + x0;  g.w01 = wx0*wy1;
    g.c11 = y1*BEVW + x1;  g.w11 = wx1*wy1;
    g.valid = 1;
    return g;
}

// Wave-run aggregation: consecutive lanes holding the same cell form a run.
__device__ __forceinline__ void run_info(int cell, int lane,
                                         bool& leader, int& runlen, int& leadlane)
{
    int prev = __shfl_up(cell, 1);
    bool change = (lane == 0) || (cell != prev);
    unsigned long long bal = __ballot(change);
    unsigned long long below = bal & (~0ull >> (63 - lane));
    leadlane = 63 - __builtin_clzll(below);
    unsigned long long above = (lane == 63) ? 0ull : (bal >> (lane + 1));
    int next = (above == 0ull) ? 64 : (lane + 1 + __builtin_ffsll((long long)above) - 1);
    runlen = next - lane;
    leader = change && (cell >= 0);
}

// ---------------- fused prep v3: validity-gated per-wave transpose + conf + histogram --
// Grid (350,12), block 256 (4 waves). Each WAVE independently handles 16 pixels.
// NEW: the wave FIRST computes geometry for its own 16 px (lanes 0..15), does its own
// run-aggregated histogram, and RETIRES if no pixel in its window is valid -- skipping
// all feat/depth loads and feat_t/conf stores (that data is provably never read:
// entries exist only for valid pixels, and place only consumes conf via valid slots).
// Valid regions are spatially coherent (vertical image strips), so 16-px granularity
// captures most of the dead traffic.
__global__ __launch_bounds__(256) void prep_kernel(
    const float* __restrict__ feat,    // [12,64,22400]
    const float* __restrict__ depth,   // [12,64,22400]
    const float* __restrict__ I_inv, const float* __restrict__ E_inv,
    const float* __restrict__ Vm,
    float* __restrict__ feat_t,        // [12,22400,64]
    float* __restrict__ conf,          // [12,22400]
    int* __restrict__ counts)          // [NBINS_PAD]
{
    __shared__ float tile[4][16][68];  // per-wave private 16px x 64ch tile (stride 68)

    const int bn   = blockIdx.y;
    const int p0   = blockIdx.x * 64;          // 22400 = 350*64 exactly, no bounds checks
    const int tid  = threadIdx.x;
    const int lane = tid & 63, wv = tid >> 6;
    const int lq   = lane & 3;                 // pixel-quad selector (4 px)
    const int lh   = lane >> 2;                // 0..15
    const int pw   = p0 + 16 * wv;             // this wave's 16-px base

    // ---- geometry + histogram for this wave's 16 px (lanes 0..15 carry real cells)
    Geo g = geo_compute(bn, pw + (lane & 15), I_inv, E_inv, Vm);
    const int myvalid = (lane < 16) && g.valid;
    const int base    = (bn / NN) * HWB;
    {
        const int cells[4] = { myvalid ? base + g.c00 : -1, myvalid ? base + g.c10 : -1,
                               myvalid ? base + g.c01 : -1, myvalid ? base + g.c11 : -1 };
#pragma unroll
        for (int k = 0; k < 4; ++k) {
            bool leader; int runlen, leadlane;
            run_info(cells[k], lane, leader, runlen, leadlane);
            if (leader) atomicAdd(&counts[cells[k]], runlen);
        }
    }
    // no valid pixel in this 16-px window -> nothing downstream ever reads our data
    if (__ballot(myvalid) == 0ull) return;

    // ---- transpose loads: f[i] covers channels {16i+lh}, pixels pw+4lq..+3
    const float* fcam = feat + (size_t)bn * CCH * HWF;
    float4 f[4];
#pragma unroll
    for (int i = 0; i < 4; ++i)
        f[i] = *(const float4*)(fcam + (size_t)(16*i + lh) * HWF + pw + 4*lq);

    // ---- depth-max loads: each lane maxes planes {lh, lh+16, lh+32, lh+48} for its quad
    const float* dcam = depth + (size_t)bn * DDE * HWF;
    float4 mx;
    {
        float4 d0 = *(const float4*)(dcam + (size_t)(lh     ) * HWF + pw + 4*lq);
        float4 d1 = *(const float4*)(dcam + (size_t)(lh + 16) * HWF + pw + 4*lq);
        float4 d2 = *(const float4*)(dcam + (size_t)(lh + 32) * HWF + pw + 4*lq);
        float4 d3 = *(const float4*)(dcam + (size_t)(lh + 48) * HWF + pw + 4*lq);
        mx = f4max(f4max(d0, d1), f4max(d2, d3));
    }

    // ---- LDS transpose write: 16 b32 writes, 2-way bank alias (free)
#pragma unroll
    for (int i = 0; i < 4; ++i) {
        tile[wv][4*lq + 0][16*i + lh] = f[i].x;
        tile[wv][4*lq + 1][16*i + lh] = f[i].y;
        tile[wv][4*lq + 2][16*i + lh] = f[i].z;
        tile[wv][4*lq + 3][16*i + lh] = f[i].w;
    }

    // ---- conf reduce across the 16 lanes sharing lq (lane bits 2..5), then store
#pragma unroll
    for (int m = 4; m <= 32; m <<= 1) {
        mx.x = fmaxf(mx.x, __shfl_xor(mx.x, m));
        mx.y = fmaxf(mx.y, __shfl_xor(mx.y, m));
        mx.z = fmaxf(mx.z, __shfl_xor(mx.z, m));
        mx.w = fmaxf(mx.w, __shfl_xor(mx.w, m));
    }
    if (lh == 0)
        *(float4*)(conf + (size_t)bn * HWF + pw + 4*lq) = mx;

    // ---- LDS read (aligned b128) + coalesced store; same-wave dep -> lgkmcnt only
    float* ocam = feat_t + (size_t)bn * HWF * CCH;
#pragma unroll
    for (int r = 0; r < 4; ++r) {
        float4 o = *(const float4*)(&tile[wv][lh][16*r + 4*lq]);
        *(float4*)(ocam + (size_t)(pw + lh) * CCH + 16*r + 4*lq) = o;
    }
}

// D1: per-256-block exclusive scan of counts
__global__ __launch_bounds__(256) void scan1_kernel(
    const int* __restrict__ counts, int* __restrict__ offsets, int* __restrict__ bsum)
{
    __shared__ int tmp[256];
    const int t = threadIdx.x;
    const int i = blockIdx.x * 256 + t;
    int v = counts[i];
    tmp[t] = v; __syncthreads();
    for (int off = 1; off < 256; off <<= 1) {
        int x = (t >= off) ? tmp[t - off] : 0;
        __syncthreads();
        tmp[t] += x;
        __syncthreads();
    }
    offsets[i] = tmp[t] - v;
    if (t == 255) bsum[blockIdx.x] = tmp[255];
}

// D2+D3 merged: each block sums preceding block-sums itself, finalizes offsets+cursor.
__global__ __launch_bounds__(256) void scan3_kernel(
    int* __restrict__ offsets, const int* __restrict__ bsum, int* __restrict__ cursor)
{
    __shared__ int s[256];
    const int t = threadIdx.x;
    int part = 0;
    for (int i = t; i < blockIdx.x; i += 256) part += bsum[i];
    s[t] = part; __syncthreads();
    for (int off = 128; off > 0; off >>= 1) {
        if (t < off) s[t] += s[t + off];
        __syncthreads();
    }
    const int i = blockIdx.x * 256 + t;
    int v = offsets[i] + s[0];
    offsets[i] = v;
    cursor[i]  = v;
}

// E: place entries (lean), run-aggregated cursor atomics + contiguous run writes
__global__ __launch_bounds__(256) void place_kernel(
    const float* __restrict__ conf,
    const float* __restrict__ I_inv, const float* __restrict__ E_inv,
    const float* __restrict__ Vm,
    int* __restrict__ cursor, int* __restrict__ ebin, uint2* __restrict__ entries)
{
    const int bn = blockIdx.y;
    const int p  = blockIdx.x * blockDim.x + threadIdx.x;
    const int lane = threadIdx.x & 63;
    const int inb = (p < HWF);
    const int pp = inb ? p : HWF - 1;
    Geo g = geo_compute(bn, pp, I_inv, E_inv, Vm);
    const int valid = inb && g.valid;
    if (__ballot(valid) == 0ull) return;   // whole wave dead -> skip conf load + run machinery
    const int base = (bn / NN) * HWB;

    const float cf = conf[(size_t)bn * HWF + pp];
    const unsigned bnp = (unsigned)(bn * HWF + pp);
    const int   cells[4] = { valid ? base + g.c00 : -1, valid ? base + g.c10 : -1,
                             valid ? base + g.c01 : -1, valid ? base + g.c11 : -1 };
    const float ws[4] = { g.w00 * cf, g.w10 * cf, g.w01 * cf, g.w11 * cf };

#pragma unroll
    for (int k = 0; k < 4; ++k) {
        bool leader; int runlen, leadlane;
        run_info(cells[k], lane, leader, runlen, leadlane);
        int pos_leader = 0;
        if (leader) pos_leader = atomicAdd(&cursor[cells[k]], runlen);
        int pos = __shfl(pos_leader, leadlane) + (lane - leadlane);
        if (valid) {
            ebin[pos]    = cells[k];
            entries[pos] = make_uint2(bnp, __float_as_uint(ws[k]));
        }
    }
}

// F: segmented gather, one wave per 64-entry chunk, lane = channel, 8-deep MLP.
__global__ __launch_bounds__(256) void gather_seg_kernel(
    const int* __restrict__ ebin, const uint2* __restrict__ entries,
    const int* __restrict__ total_ptr,
    const float* __restrict__ feat_t, float* __restrict__ acc)
{
    const int lane = threadIdx.x & 63, wv = threadIdx.x >> 6;
    const int chunk = blockIdx.x * 4 + wv;
    const int total = *total_ptr;
    const int start = chunk * 64;
    if (start >= total) return;
    const int m = min(64, total - start);   // multiple of 4

    int myb = -1;
    uint2 mye = make_uint2(0u, 0u);
    if (lane < m) { myb = ebin[start + lane]; mye = entries[start + lane]; }

    float a = 0.0f;
    int j = 0;
    for (; j + 8 <= m; j += 8) {
        int bb[9]; unsigned xx[8], ww[8];
#pragma unroll
        for (int k = 0; k < 8; ++k) {
            bb[k] = __shfl(myb, j + k);
            xx[k] = (unsigned)__shfl((int)mye.x, j + k);
            ww[k] = (unsigned)__shfl((int)mye.y, j + k);
        }
        bb[8] = (j + 8 < 64) ? __shfl(myb, j + 8) : -2;
        float f[8];
#pragma unroll
        for (int k = 0; k < 8; ++k)
            f[k] = feat_t[(size_t)xx[k] * CCH + lane];   // 8 indep coalesced 256B loads
#pragma unroll
        for (int k = 0; k < 8; ++k) {
            a = fmaf(f[k], __uint_as_float(ww[k]), a);
            if (bb[k] != bb[k + 1]) { atomicAdd(&acc[(size_t)bb[k] * CCH + lane], a); a = 0.0f; }
        }
    }
    if (j < m) {   // 4-entry tail
        int bb[5]; unsigned xx[4], ww[4];
#pragma unroll
        for (int k = 0; k < 4; ++k) {
            bb[k] = __shfl(myb, j + k);
            xx[k] = (unsigned)__shfl((int)mye.x, j + k);
            ww[k] = (unsigned)__shfl((int)mye.y, j + k);
        }
        bb[4] = (j + 4 < 64) ? __shfl(myb, j + 4) : -2;
        float f[4];
#pragma unroll
        for (int k = 0; k < 4; ++k)
            f[k] = feat_t[(size_t)xx[k] * CCH + lane];
#pragma unroll
        for (int k = 0; k < 4; ++k) {
            a = fmaf(f[k], __uint_as_float(ww[k]), a);
            if (bb[k] != bb[k + 1]) { atomicAdd(&acc[(size_t)bb[k] * CCH + lane], a); a = 0.0f; }
        }
    }
}

// G: out[b][c][cell] = acc[b*HWB+cell][c] / 6 -- float4 both sides via LDS tile
__global__ __launch_bounds__(256) void finalize_kernel(
    const float* __restrict__ acc, float* __restrict__ out)
{
    __shared__ float t[64][66];
    const int b     = blockIdx.y;
    const int cell0 = blockIdx.x * 64;
    const int cc    = threadIdx.x >> 2;   // read: cell row / write: channel
    const int q     = threadIdx.x & 3;

    const float* abase = acc + ((size_t)b * HWB + cell0) * CCH;
#pragma unroll
    for (int i = 0; i < 4; ++i) {
        const int cg = q + 4 * i;
        float4 f = *(const float4*)(abase + (size_t)cc * CCH + 4 * cg);
        t[cc][4*cg+0] = f.x; t[cc][4*cg+1] = f.y;
        t[cc][4*cg+2] = f.z; t[cc][4*cg+3] = f.w;
    }
    __syncthreads();
    float* obase = out + (size_t)b * CCH * HWB + cell0;
#pragma unroll
    for (int i = 0; i < 4; ++i) {
        const int lg = q + 4 * i;           // cell-group
        float4 o;
        o.x = t[4*lg+0][cc] * (1.0f/6.0f);
        o.y = t[4*lg+1][cc] * (1.0f/6.0f);
        o.z = t[4*lg+2][cc] * (1.0f/6.0f);
        o.w = t[4*lg+3][cc] * (1.0f/6.0f);
        *(float4*)(obase + (size_t)cc * HWB + 4 * lg) = o;
    }
}

// ---------------- fallback (round-4 atomic splat) if ws too small ----------------
__global__ __launch_bounds__(256) void splat_kernel(
    const float* __restrict__ feat, const float* __restrict__ depth,
    const float* __restrict__ I_inv, const float* __restrict__ E_inv,
    const float* __restrict__ Vm, float* __restrict__ acc)
{
    __shared__ float fshare[64][65];
    __shared__ float cpart2[4][64];
    const int bn = blockIdx.y, b = bn / NN, p0 = blockIdx.x * 64;
    const int lane = threadIdx.x & 63, wv = threadIdx.x >> 6;
    const float* fbase = feat + (size_t)bn * CCH * HWF + p0;
#pragma unroll
    for (int c = wv; c < CCH; c += 4)
        fshare[lane][c] = fbase[(size_t)c * HWF + lane];
    const float* dbase = depth + (size_t)bn * DDE * HWF + p0;
    float m = dbase[(size_t)(wv * 16) * HWF + lane];
#pragma unroll
    for (int d = wv * 16 + 1; d < wv * 16 + 16; ++d)
        m = fmaxf(m, dbase[(size_t)d * HWF + lane]);
    cpart2[wv][lane] = m;
    __syncthreads();
    float* ab = acc + ((size_t)b * HWB) * CCH + lane;
    for (int s = wv * 16; s < wv * 16 + 16; ++s) {
        Geo g = geo_compute(bn, p0 + s, I_inv, E_inv, Vm);
        if (!g.valid) continue;
        float cf = fmaxf(fmaxf(cpart2[0][s], cpart2[1][s]), fmaxf(cpart2[2][s], cpart2[3][s]));
        float f = fshare[s][lane];
        atomicAdd(ab + (size_t)g.c00 * CCH, f * (g.w00 * cf));
        atomicAdd(ab + (size_t)g.c10 * CCH, f * (g.w10 * cf));
        atomicAdd(ab + (size_t)g.c01 * CCH, f * (g.w01 * cf));
        atomicAdd(ab + (size_t)g.c11 * CCH, f * (g.w11 * cf));
    }
}

extern "C" void kernel_launch(void* const* d_in, const int* in_sizes, int n_in,
                              void* d_out, int out_size, void* d_ws, size_t ws_size,
                              hipStream_t stream) {
    const float* feat  = (const float*)d_in[0];
    const float* depth = (const float*)d_in[1];
    const float* I_inv = (const float*)d_in[2];
    const float* E_inv = (const float*)d_in[3];
    const float* Vm    = (const float*)d_in[4];
    float* out = (float*)d_out;

    size_t off = 0;
    char* wsb = (char*)d_ws;
    auto carve = [&](size_t bytes) -> void* {
        void* p = wsb + off; off += (bytes + 255) & ~(size_t)255; return p;
    };
    // acc and counts adjacent -> single memset (acc bytes are 256B-multiple)
    float* feat_t  = (float*)carve((size_t)BB * NN * CCH * HWF * 4);  // 68.8 MB
    float* acc     = (float*)carve(ACC_ELEMS * 4);                    // 20.5 MB
    int*   counts  = (int*)  carve((NBINS_PAD + 256) * 4);            // 0.33 MB
    uint2* entries = (uint2*)carve((size_t)MAXENT * 8);               //  8.6 MB
    int*   ebin    = (int*)  carve((size_t)MAXENT * 4);               //  4.3 MB
    float* conf    = (float*)carve((size_t)BB * NN * HWF * 4);        //  1.1 MB
    int*   offsets = (int*)  carve((NBINS_PAD + 256) * 4);
    int*   cursor  = (int*)  carve((NBINS_PAD + 256) * 4);
    int*   bsum    = (int*)  carve(NSCANB * 4);

    if (off <= ws_size) {
        hipMemsetAsync(acc, 0, ACC_ELEMS * 4 + (NBINS_PAD + 256) * 4, stream);

        dim3 pgrid(HWF / 64, BB * NN);                 // (350,12)
        prep_kernel<<<pgrid, 256, 0, stream>>>(feat, depth, I_inv, E_inv, Vm,
                                               feat_t, conf, counts);

        scan1_kernel<<<NSCANB, 256, 0, stream>>>(counts, offsets, bsum);
        scan3_kernel<<<NSCANB, 256, 0, stream>>>(offsets, bsum, cursor);

        dim3 plgrid((HWF + 255) / 256, BB * NN);       // (88,12)
        place_kernel<<<plgrid, 256, 0, stream>>>(conf, I_inv, E_inv, Vm,
                                                 cursor, ebin, entries);

        gather_seg_kernel<<<NCHUNK / 4, 256, 0, stream>>>(
            ebin, entries, offsets + NBINS, feat_t, acc);

        dim3 fgrid(HWB / 64, BB);                      // (625,2)
        finalize_kernel<<<fgrid, 256, 0, stream>>>(acc, out);
    } else {
        float* acc0 = (float*)d_ws;
        hipMemsetAsync(acc0, 0, ACC_ELEMS * 4, stream);
        dim3 grid(HWF / 64, BB * NN);
        splat_kernel<<<grid, 256, 0, stream>>>(feat, depth, I_inv, E_inv, Vm, acc0);
        dim3 fgrid(HWB / 64, BB);
        finalize_kernel<<<fgrid, 625 == 625 ? 256 : 256, 0, stream>>>(acc0, out);
    }
}

// Round 3
// 247.277 us; speedup vs baseline: 1.6914x; 1.6914x over previous
//
#include <hip/hip_runtime.h>

// LiftSplatBEV: B=2, N=6, C=64, HF=112, WF=200, D=64, BEV 200x200
#define BB   2
#define NN   6
#define CCH  64
#define HFE  112
#define WFE  200
#define DDE  64
#define HWF  (HFE*WFE)      // 22400 feature pixels (= 350*64); /4 = 5600 float4 groups
#define HWF4 (HWF/4)
#define BEVH 200
#define BEVW 200
#define HWB  (BEVH*BEVW)    // 40000 BEV cells
#define NBINS (BB*HWB)      // 80000 (b,cell) bins
#define NBINS_PAD 81920     // 320*256
#define NSCANB (NBINS_PAD/256)  // 320
#define MAXENT1 (BB*NN*HWF)     // 268,800 max entries (ONE per valid pixel)
#define NCHUNK1 (MAXENT1/64)    // 4200 64-entry chunks
#define ACC_ELEMS ((size_t)BB*HWB*CCH)   // channel-last [b*HWB+cell][c]

__device__ __forceinline__ float4 f4max(float4 a, float4 b) {
    return make_float4(fmaxf(a.x,b.x), fmaxf(a.y,b.y), fmaxf(a.z,b.z), fmaxf(a.w,b.w));
}

// ---------------- shared geometry (bug-faithful to reference) ----------------
struct Geo {
    int valid;
    int c00, c10, c01, c11;
    float w00, w10, w01, w11;
};

__device__ __forceinline__ Geo geo_compute(int bn, int p,
    const float* __restrict__ I_inv, const float* __restrict__ E_inv,
    const float* __restrict__ Vm)
{
    Geo g; g.valid = 0;
    // bug-faithful w-outer flatten: u = p/112, v = p%112
    const float u = (float)(p / HFE);
    const float v = (float)(p % HFE);
    const float* Ii = I_inv + bn * 9;
    const float* Ei = E_inv + bn * 16;
    float cx = Ii[0]*u + Ii[1]*v + Ii[2];
    float cy = Ii[3]*u + Ii[4]*v + Ii[5];
    float cz = Ii[6]*u + Ii[7]*v + Ii[8];
    float tx = Ei[3], ty = Ei[7], tz = Ei[11];
    float dx = Ei[0]*cx + Ei[1]*cy + Ei[2] *cz + tx;   // includes translation (bug-faithful)
    float dy = Ei[4]*cx + Ei[5]*cy + Ei[6] *cz + ty;
    float dz = Ei[8]*cx + Ei[9]*cy + Ei[10]*cz + tz;
    float s  = -tz / fmaxf(dz, 1e-6f);
    float ex = tx + dx * s;
    float ey = ty + dy * s;
    float prx = Vm[0]*ex + Vm[1]*ey + Vm[2];
    float pry = Vm[3]*ex + Vm[4]*ey + Vm[5];
    float prz = Vm[6]*ex + Vm[7]*ey + Vm[8];
    float den = fmaxf(prz, 1e-7f);
    float bx = prx / den, by = pry / den;
    // bug-faithful gx->px roundtrip, same association order as reference
    float gx = bx / (float)(BEVW-1) * 2.0f - 1.0f;
    float gy = by / (float)(BEVH-1) * 2.0f - 1.0f;
    float px = (gx + 1.0f) * (float)(BEVW-1) / 2.0f;
    float py = (gy + 1.0f) * (float)(BEVH-1) / 2.0f;
    float x0f = fminf(fmaxf(floorf(px), 0.0f), (float)(BEVW-1));
    float y0f = fminf(fmaxf(floorf(py), 0.0f), (float)(BEVH-1));
    float x1f = fminf(x0f + 1.0f, (float)(BEVW-1));
    float y1f = fminf(y0f + 1.0f, (float)(BEVH-1));
    // far-edge-degenerate slots cancel exactly in the fp64 np reference: skip
    if (x0f == x1f || y0f == y1f) return g;
    float wx0 = x1f - px, wx1 = px - x0f;
    float wy0 = y1f - py, wy1 = py - y0f;
    int x0 = (int)x0f, x1 = (int)x1f, y0 = (int)y0f, y1 = (int)y1f;
    g.c00 = y0*BEVW + x0;  g.w00 = wx0*wy0;
    g.c10 = y0*BEVW + x1;  g.w10 = wx1*wy0;
    g.c01 = y1*BEVW + x0;  g.w01 = wx0*wy1;
    g.c11 = y1*BEVW + x1;  g.w11 = wx1*wy1;
    // NOTE: for valid pixels x1 = x0+1, y1 = y0+1  =>  c10/c01/c11 = c00 + {1,200,201}
    g.valid = 1;
    return g;
}

// Wave-run aggregation: consecutive lanes holding the same cell form a run.
__device__ __forceinline__ void run_info(int cell, int lane,
                                         bool& leader, int& runlen, int& leadlane)
{
    int prev = __shfl_up(cell, 1);
    bool change = (lane == 0) || (cell != prev);
    unsigned long long bal = __ballot(change);
    unsigned long long below = bal & (~0ull >> (63 - lane));
    leadlane = 63 - __builtin_clzll(below);
    unsigned long long above = (lane == 63) ? 0ull : (bal >> (lane + 1));
    int next = (above == 0ull) ? 64 : (lane + 1 + __builtin_ffsll((long long)above) - 1);
    runlen = next - lane;
    leader = change && (cell >= 0);
}

__device__ __forceinline__ unsigned pack2w(float a, float b) {
    unsigned ua = __float2uint_rn(a * 65535.0f);
    unsigned ub = __float2uint_rn(b * 65535.0f);
    return ua | (ub << 16);
}

// ---------------- fused prep (round-1 form): per-wave transpose + conf + c00 histogram -
// Grid (350,12), block 256 (4 waves). Loads issue FIRST (geometry last: round-2 showed
// geometry-before-loads serializes the wave and costs 2x). Histogram now counts ONE
// entry per valid pixel (its c00 bin).
__global__ __launch_bounds__(256) void prep_kernel(
    const float* __restrict__ feat,    // [12,64,22400]
    const float* __restrict__ depth,   // [12,64,22400]
    const float* __restrict__ I_inv, const float* __restrict__ E_inv,
    const float* __restrict__ Vm,
    float* __restrict__ feat_t,        // [12,22400,64]
    float* __restrict__ conf,          // [12,22400]
    int* __restrict__ counts)          // [NBINS_PAD]
{
    __shared__ float tile[4][16][68];  // per-wave private 16px x 64ch tile (stride 68)

    const int bn   = blockIdx.y;
    const int p0   = blockIdx.x * 64;          // 22400 = 350*64 exactly, no bounds checks
    const int tid  = threadIdx.x;
    const int lane = tid & 63, wv = tid >> 6;
    const int lq   = lane & 3;                 // pixel-quad selector (4 px)
    const int lh   = lane >> 2;                // 0..15
    const int pw   = p0 + 16 * wv;             // this wave's 16-px base

    // ---- transpose loads: f[i] covers channels {16i+lh}, pixels pw+4lq..+3
    const float* fcam = feat + (size_t)bn * CCH * HWF;
    float4 f[4];
#pragma unroll
    for (int i = 0; i < 4; ++i)
        f[i] = *(const float4*)(fcam + (size_t)(16*i + lh) * HWF + pw + 4*lq);

    // ---- depth-max loads: each lane maxes planes {lh, lh+16, lh+32, lh+48} for its quad
    const float* dcam = depth + (size_t)bn * DDE * HWF;
    float4 mx;
    {
        float4 d0 = *(const float4*)(dcam + (size_t)(lh     ) * HWF + pw + 4*lq);
        float4 d1 = *(const float4*)(dcam + (size_t)(lh + 16) * HWF + pw + 4*lq);
        float4 d2 = *(const float4*)(dcam + (size_t)(lh + 32) * HWF + pw + 4*lq);
        float4 d3 = *(const float4*)(dcam + (size_t)(lh + 48) * HWF + pw + 4*lq);
        mx = f4max(f4max(d0, d1), f4max(d2, d3));
    }

    // ---- LDS transpose write: 16 b32 writes, 2-way bank alias (free)
#pragma unroll
    for (int i = 0; i < 4; ++i) {
        tile[wv][4*lq + 0][16*i + lh] = f[i].x;
        tile[wv][4*lq + 1][16*i + lh] = f[i].y;
        tile[wv][4*lq + 2][16*i + lh] = f[i].z;
        tile[wv][4*lq + 3][16*i + lh] = f[i].w;
    }

    // ---- conf reduce across the 16 lanes sharing lq (lane bits 2..5), then store
#pragma unroll
    for (int m = 4; m <= 32; m <<= 1) {
        mx.x = fmaxf(mx.x, __shfl_xor(mx.x, m));
        mx.y = fmaxf(mx.y, __shfl_xor(mx.y, m));
        mx.z = fmaxf(mx.z, __shfl_xor(mx.z, m));
        mx.w = fmaxf(mx.w, __shfl_xor(mx.w, m));
    }
    if (lh == 0)
        *(float4*)(conf + (size_t)bn * HWF + pw + 4*lq) = mx;

    // ---- LDS read (aligned b128) + coalesced store; same-wave dep -> lgkmcnt only
    float* ocam = feat_t + (size_t)bn * HWF * CCH;
#pragma unroll
    for (int r = 0; r < 4; ++r) {
        float4 o = *(const float4*)(&tile[wv][lh][16*r + 4*lq]);
        *(float4*)(ocam + (size_t)(pw + lh) * CCH + 16*r + 4*lq) = o;
    }

    // ---- histogram: wave 0 covers the block's 64-px window, c00 bin only
    if (wv == 0) {
        Geo g = geo_compute(bn, p0 + lane, I_inv, E_inv, Vm);
        const int base = (bn / NN) * HWB;
        const int cell = g.valid ? base + g.c00 : -1;
        bool leader; int runlen, leadlane;
        run_info(cell, lane, leader, runlen, leadlane);
        if (leader) atomicAdd(&counts[cell], runlen);
    }
}

// D1: per-256-block exclusive scan of counts
__global__ __launch_bounds__(256) void scan1_kernel(
    const int* __restrict__ counts, int* __restrict__ offsets, int* __restrict__ bsum)
{
    __shared__ int tmp[256];
    const int t = threadIdx.x;
    const int i = blockIdx.x * 256 + t;
    int v = counts[i];
    tmp[t] = v; __syncthreads();
    for (int off = 1; off < 256; off <<= 1) {
        int x = (t >= off) ? tmp[t - off] : 0;
        __syncthreads();
        tmp[t] += x;
        __syncthreads();
    }
    offsets[i] = tmp[t] - v;
    if (t == 255) bsum[blockIdx.x] = tmp[255];
}

// D2+D3 merged: each block sums preceding block-sums itself, finalizes offsets+cursor.
__global__ __launch_bounds__(256) void scan3_kernel(
    int* __restrict__ offsets, const int* __restrict__ bsum, int* __restrict__ cursor)
{
    __shared__ int s[256];
    const int t = threadIdx.x;
    int part = 0;
    for (int i = t; i < blockIdx.x; i += 256) part += bsum[i];
    s[t] = part; __syncthreads();
    for (int off = 128; off > 0; off >>= 1) {
        if (t < off) s[t] += s[t + off];
        __syncthreads();
    }
    const int i = blockIdx.x * 256 + t;
    int v = offsets[i] + s[0];
    offsets[i] = v;
    cursor[i]  = v;
}

// E: place ONE entry per valid pixel: uint4{bin(c00), pixel, w00|w10, w01|w11}
//    weights (x conf) packed u16 fixed-point (err <= 8e-6, far below fp32 tolerance).
__global__ __launch_bounds__(256) void place_kernel(
    const float* __restrict__ conf,
    const float* __restrict__ I_inv, const float* __restrict__ E_inv,
    const float* __restrict__ Vm,
    int* __restrict__ cursor, uint4* __restrict__ entries)
{
    const int bn = blockIdx.y;
    const int p  = blockIdx.x * blockDim.x + threadIdx.x;
    const int lane = threadIdx.x & 63;
    const int inb = (p < HWF);
    const int pp = inb ? p : HWF - 1;
    Geo g = geo_compute(bn, pp, I_inv, E_inv, Vm);
    const int valid = inb && g.valid;
    if (__ballot(valid) == 0ull) return;
    const int base = (bn / NN) * HWB;
    const int bin  = valid ? base + g.c00 : -1;

    bool leader; int runlen, leadlane;
    run_info(bin, lane, leader, runlen, leadlane);
    int pos_leader = 0;
    if (leader) pos_leader = atomicAdd(&cursor[bin], runlen);
    int pos = __shfl(pos_leader, leadlane) + (lane - leadlane);
    if (valid) {
        const float cf = conf[(size_t)bn * HWF + pp];
        entries[pos] = make_uint4((unsigned)bin, (unsigned)(bn * HWF + pp),
                                  pack2w(g.w00 * cf, g.w10 * cf),
                                  pack2w(g.w01 * cf, g.w11 * cf));
    }
}

// F: segmented gather, one wave per 64-entry chunk, lane = channel.
//    One feat_t row read per PIXEL (not per corner); 4 register accumulators per run;
//    4 atomics per run end to bin + {0,1,200,201}.
__global__ __launch_bounds__(256) void gather_seg_kernel(
    const uint4* __restrict__ entries, const int* __restrict__ total_ptr,
    const float* __restrict__ feat_t, float* __restrict__ acc)
{
    const int lane = threadIdx.x & 63, wv = threadIdx.x >> 6;
    const int chunk = blockIdx.x * 4 + wv;
    const int total = *total_ptr;
    const int start = chunk * 64;
    if (start >= total) return;
    const int m = min(64, total - start);

    int myb = -1;
    uint4 mye = make_uint4(0u, 0u, 0u, 0u);
    if (lane < m) { mye = entries[start + lane]; myb = (int)mye.x; }

    const float inv = 1.0f / 65535.0f;
    float a00 = 0.f, a10 = 0.f, a01 = 0.f, a11 = 0.f;
    for (int j = 0; j < 64; j += 8) {
        int bb[9]; unsigned px[8], wA[8], wB[8];
#pragma unroll
        for (int k = 0; k < 8; ++k) {
            bb[k] = __shfl(myb, j + k);
            px[k] = (unsigned)__shfl((int)mye.y, j + k);
            wA[k] = (unsigned)__shfl((int)mye.z, j + k);
            wB[k] = (unsigned)__shfl((int)mye.w, j + k);
        }
        bb[8] = (j + 8 < 64) ? __shfl(myb, j + 8) : -2;
        float f[8];
#pragma unroll
        for (int k = 0; k < 8; ++k)
            f[k] = (bb[k] >= 0) ? feat_t[(size_t)px[k] * CCH + lane] : 0.0f;
#pragma unroll
        for (int k = 0; k < 8; ++k) {
            a00 = fmaf(f[k], (float)(wA[k] & 0xffffu) * inv, a00);
            a10 = fmaf(f[k], (float)(wA[k] >> 16)     * inv, a10);
            a01 = fmaf(f[k], (float)(wB[k] & 0xffffu) * inv, a01);
            a11 = fmaf(f[k], (float)(wB[k] >> 16)     * inv, a11);
            if (bb[k] != bb[k + 1]) {
                if (bb[k] >= 0) {
                    float* ab = acc + (size_t)bb[k] * CCH + lane;
                    atomicAdd(ab,                       a00);
                    atomicAdd(ab + (size_t)1   * CCH,   a10);
                    atomicAdd(ab + (size_t)200 * CCH,   a01);
                    atomicAdd(ab + (size_t)201 * CCH,   a11);
                }
                a00 = a10 = a01 = a11 = 0.f;
            }
        }
    }
}

// G: out[b][c][cell] = acc[b*HWB+cell][c] / 6 -- float4 both sides via LDS tile
__global__ __launch_bounds__(256) void finalize_kernel(
    const float* __restrict__ acc, float* __restrict__ out)
{
    __shared__ float t[64][66];
    const int b     = blockIdx.y;
    const int cell0 = blockIdx.x * 64;
    const int cc    = threadIdx.x >> 2;   // read: cell row / write: channel
    const int q     = threadIdx.x & 3;

    const float* abase = acc + ((size_t)b * HWB + cell0) * CCH;
#pragma unroll
    for (int i = 0; i < 4; ++i) {
        const int cg = q + 4 * i;
        float4 f = *(const float4*)(abase + (size_t)cc * CCH + 4 * cg);
        t[cc][4*cg+0] = f.x; t[cc][4*cg+1] = f.y;
        t[cc][4*cg+2] = f.z; t[cc][4*cg+3] = f.w;
    }
    __syncthreads();
    float* obase = out + (size_t)b * CCH * HWB + cell0;
#pragma unroll
    for (int i = 0; i < 4; ++i) {
        const int lg = q + 4 * i;           // cell-group
        float4 o;
        o.x = t[4*lg+0][cc] * (1.0f/6.0f);
        o.y = t[4*lg+1][cc] * (1.0f/6.0f);
        o.z = t[4*lg+2][cc] * (1.0f/6.0f);
        o.w = t[4*lg+3][cc] * (1.0f/6.0f);
        *(float4*)(obase + (size_t)cc * HWB + 4 * lg) = o;
    }
}

// ---------------- fallback (round-4 atomic splat) if ws too small ----------------
__global__ __launch_bounds__(256) void splat_kernel(
    const float* __restrict__ feat, const float* __restrict__ depth,
    const float* __restrict__ I_inv, const float* __restrict__ E_inv,
    const float* __restrict__ Vm, float* __restrict__ acc)
{
    __shared__ float fshare[64][65];
    __shared__ float cpart2[4][64];
    const int bn = blockIdx.y, b = bn / NN, p0 = blockIdx.x * 64;
    const int lane = threadIdx.x & 63, wv = threadIdx.x >> 6;
    const float* fbase = feat + (size_t)bn * CCH * HWF + p0;
#pragma unroll
    for (int c = wv; c < CCH; c += 4)
        fshare[lane][c] = fbase[(size_t)c * HWF + lane];
    const float* dbase = depth + (size_t)bn * DDE * HWF + p0;
    float m = dbase[(size_t)(wv * 16) * HWF + lane];
#pragma unroll
    for (int d = wv * 16 + 1; d < wv * 16 + 16; ++d)
        m = fmaxf(m, dbase[(size_t)d * HWF + lane]);
    cpart2[wv][lane] = m;
    __syncthreads();
    float* ab = acc + ((size_t)b * HWB) * CCH + lane;
    for (int s = wv * 16; s < wv * 16 + 16; ++s) {
        Geo g = geo_compute(bn, p0 + s, I_inv, E_inv, Vm);
        if (!g.valid) continue;
        float cf = fmaxf(fmaxf(cpart2[0][s], cpart2[1][s]), fmaxf(cpart2[2][s], cpart2[3][s]));
        float f = fshare[s][lane];
        atomicAdd(ab + (size_t)g.c00 * CCH, f * (g.w00 * cf));
        atomicAdd(ab + (size_t)g.c10 * CCH, f * (g.w10 * cf));
        atomicAdd(ab + (size_t)g.c01 * CCH, f * (g.w01 * cf));
        atomicAdd(ab + (size_t)g.c11 * CCH, f * (g.w11 * cf));
    }
}

extern "C" void kernel_launch(void* const* d_in, const int* in_sizes, int n_in,
                              void* d_out, int out_size, void* d_ws, size_t ws_size,
                              hipStream_t stream) {
    const float* feat  = (const float*)d_in[0];
    const float* depth = (const float*)d_in[1];
    const float* I_inv = (const float*)d_in[2];
    const float* E_inv = (const float*)d_in[3];
    const float* Vm    = (const float*)d_in[4];
    float* out = (float*)d_out;

    size_t off = 0;
    char* wsb = (char*)d_ws;
    auto carve = [&](size_t bytes) -> void* {
        void* p = wsb + off; off += (bytes + 255) & ~(size_t)255; return p;
    };
    // acc and counts adjacent -> single memset (acc bytes are 256B-multiple)
    float* feat_t  = (float*)carve((size_t)BB * NN * CCH * HWF * 4);  // 68.8 MB
    float* acc     = (float*)carve(ACC_ELEMS * 4);                    // 20.5 MB
    int*   counts  = (int*)  carve((NBINS_PAD + 256) * 4);            // 0.33 MB
    uint4* entries = (uint4*)carve((size_t)MAXENT1 * 16);             //  4.3 MB
    float* conf    = (float*)carve((size_t)BB * NN * HWF * 4);        //  1.1 MB
    int*   offsets = (int*)  carve((NBINS_PAD + 256) * 4);
    int*   cursor  = (int*)  carve((NBINS_PAD + 256) * 4);
    int*   bsum    = (int*)  carve(NSCANB * 4);

    if (off <= ws_size) {
        hipMemsetAsync(acc, 0, ACC_ELEMS * 4 + (NBINS_PAD + 256) * 4, stream);

        dim3 pgrid(HWF / 64, BB * NN);                 // (350,12)
        prep_kernel<<<pgrid, 256, 0, stream>>>(feat, depth, I_inv, E_inv, Vm,
                                               feat_t, conf, counts);

        scan1_kernel<<<NSCANB, 256, 0, stream>>>(counts, offsets, bsum);
        scan3_kernel<<<NSCANB, 256, 0, stream>>>(offsets, bsum, cursor);

        dim3 plgrid((HWF + 255) / 256, BB * NN);       // (88,12)
        place_kernel<<<plgrid, 256, 0, stream>>>(conf, I_inv, E_inv, Vm,
                                                 cursor, entries);

        gather_seg_kernel<<<NCHUNK1 / 4, 256, 0, stream>>>(
            entries, offsets + NBINS, feat_t, acc);

        dim3 fgrid(HWB / 64, BB);                      // (625,2)
        finalize_kernel<<<fgrid, 256, 0, stream>>>(acc, out);
    } else {
        float* acc0 = (float*)d_ws;
        hipMemsetAsync(acc0, 0, ACC_ELEMS * 4, stream);
        dim3 grid(HWF / 64, BB * NN);
        splat_kernel<<<grid, 256, 0, stream>>>(feat, depth, I_inv, E_inv, Vm, acc0);
        dim3 fgrid(HWB / 64, BB);
        finalize_kernel<<<fgrid, 256, 0, stream>>>(acc0, out);
    }
}

// Round 5
// 246.683 us; speedup vs baseline: 1.6955x; 1.0024x over previous
//
#include <hip/hip_runtime.h>

// LiftSplatBEV: B=2, N=6, C=64, HF=112, WF=200, D=64, BEV 200x200
#define BB   2
#define NN   6
#define CCH  64
#define HFE  112
#define WFE  200
#define DDE  64
#define HWF  (HFE*WFE)      // 22400 feature pixels (= 350*64); /4 = 5600 float4 groups
#define HWF4 (HWF/4)
#define BEVH 200
#define BEVW 200
#define HWB  (BEVH*BEVW)    // 40000 BEV cells
#define NBINS (BB*HWB)      // 80000 (b,cell) bins
#define NBINS_PAD 81920     // 320*256
#define NSCANB (NBINS_PAD/256)  // 320
#define MAXENT1 (BB*NN*HWF)     // 268,800 max entries (ONE per valid pixel)
#define NCHUNK1 (MAXENT1/64)    // 4200 64-entry chunks
#define ACC_ELEMS ((size_t)BB*HWB*CCH)   // channel-last [b*HWB+cell][c]

__device__ __forceinline__ float4 f4max(float4 a, float4 b) {
    return make_float4(fmaxf(a.x,b.x), fmaxf(a.y,b.y), fmaxf(a.z,b.z), fmaxf(a.w,b.w));
}

// ---------------- shared geometry (bug-faithful to reference) ----------------
struct Geo {
    int valid;
    int c00, c10, c01, c11;
    float w00, w10, w01, w11;
};

__device__ __forceinline__ Geo geo_compute(int bn, int p,
    const float* __restrict__ I_inv, const float* __restrict__ E_inv,
    const float* __restrict__ Vm)
{
    Geo g; g.valid = 0;
    // bug-faithful w-outer flatten: u = p/112, v = p%112
    const float u = (float)(p / HFE);
    const float v = (float)(p % HFE);
    const float* Ii = I_inv + bn * 9;
    const float* Ei = E_inv + bn * 16;
    float cx = Ii[0]*u + Ii[1]*v + Ii[2];
    float cy = Ii[3]*u + Ii[4]*v + Ii[5];
    float cz = Ii[6]*u + Ii[7]*v + Ii[8];
    float tx = Ei[3], ty = Ei[7], tz = Ei[11];
    float dx = Ei[0]*cx + Ei[1]*cy + Ei[2] *cz + tx;   // includes translation (bug-faithful)
    float dy = Ei[4]*cx + Ei[5]*cy + Ei[6] *cz + ty;
    float dz = Ei[8]*cx + Ei[9]*cy + Ei[10]*cz + tz;
    float s  = -tz / fmaxf(dz, 1e-6f);
    float ex = tx + dx * s;
    float ey = ty + dy * s;
    float prx = Vm[0]*ex + Vm[1]*ey + Vm[2];
    float pry = Vm[3]*ex + Vm[4]*ey + Vm[5];
    float prz = Vm[6]*ex + Vm[7]*ey + Vm[8];
    float den = fmaxf(prz, 1e-7f);
    float bx = prx / den, by = pry / den;
    // bug-faithful gx->px roundtrip, same association order as reference
    float gx = bx / (float)(BEVW-1) * 2.0f - 1.0f;
    float gy = by / (float)(BEVH-1) * 2.0f - 1.0f;
    float px = (gx + 1.0f) * (float)(BEVW-1) / 2.0f;
    float py = (gy + 1.0f) * (float)(BEVH-1) / 2.0f;
    float x0f = fminf(fmaxf(floorf(px), 0.0f), (float)(BEVW-1));
    float y0f = fminf(fmaxf(floorf(py), 0.0f), (float)(BEVH-1));
    float x1f = fminf(x0f + 1.0f, (float)(BEVW-1));
    float y1f = fminf(y0f + 1.0f, (float)(BEVH-1));
    // far-edge-degenerate slots cancel exactly in the fp64 np reference: skip
    if (x0f == x1f || y0f == y1f) return g;
    float wx0 = x1f - px, wx1 = px - x0f;
    float wy0 = y1f - py, wy1 = py - y0f;
    int x0 = (int)x0f, x1 = (int)x1f, y0 = (int)y0f, y1 = (int)y1f;
    g.c00 = y0*BEVW + x0;  g.w00 = wx0*wy0;
    g.c10 = y0*BEVW + x1;  g.w10 = wx1*wy0;
    g.c01 = y1*BEVW + x0;  g.w01 = wx0*wy1;
    g.c11 = y1*BEVW + x1;  g.w11 = wx1*wy1;
    // NOTE: for valid pixels x1 = x0+1, y1 = y0+1  =>  c10/c01/c11 = c00 + {1,200,201}
    g.valid = 1;
    return g;
}

// Wave-run aggregation: consecutive lanes holding the same cell form a run.
__device__ __forceinline__ void run_info(int cell, int lane,
                                         bool& leader, int& runlen, int& leadlane)
{
    int prev = __shfl_up(cell, 1);
    bool change = (lane == 0) || (cell != prev);
    unsigned long long bal = __ballot(change);
    unsigned long long below = bal & (~0ull >> (63 - lane));
    leadlane = 63 - __builtin_clzll(below);
    unsigned long long above = (lane == 63) ? 0ull : (bal >> (lane + 1));
    int next = (above == 0ull) ? 64 : (lane + 1 + __builtin_ffsll((long long)above) - 1);
    runlen = next - lane;
    leader = change && (cell >= 0);
}

__device__ __forceinline__ unsigned pack2w(float a, float b) {
    unsigned ua = __float2uint_rn(a * 65535.0f);
    unsigned ub = __float2uint_rn(b * 65535.0f);
    return ua | (ub << 16);
}

// ---------------- fused prep v4: 32-px-per-wave, loads-first, distributed histogram ----
// Grid (175,12), block 256 (4 waves). Each WAVE handles 32 px as two 16-px subtiles
// through ONE reused wave-private 16x68 LDS tile (same-wave WAR -> lgkmcnt only, no
// barriers). All 16 global float4 loads issue up front (256 B/lane in flight) and are
// consumed in issue order. Histogram is distributed: each wave does geo for its own
// 32 px on lanes 0..31 (removes round-3's wave-0 tail asymmetry; counts identical,
// runs split at 32-px boundaries).
__global__ __launch_bounds__(256) void prep_kernel(
    const float* __restrict__ feat,    // [12,64,22400]
    const float* __restrict__ depth,   // [12,64,22400]
    const float* __restrict__ I_inv, const float* __restrict__ E_inv,
    const float* __restrict__ Vm,
    float* __restrict__ feat_t,        // [12,22400,64]
    float* __restrict__ conf,          // [12,22400]
    int* __restrict__ counts)          // [NBINS_PAD]
{
    __shared__ float tile[4][16][68];  // per-wave private 16px x 64ch tile (stride 68)

    const int bn   = blockIdx.y;
    const int p0   = blockIdx.x * 128;         // 22400 = 175*128 exactly
    const int tid  = threadIdx.x;
    const int lane = tid & 63, wv = tid >> 6;
    const int lq   = lane & 3;                 // pixel-quad selector (4 px)
    const int lh   = lane >> 2;                // 0..15
    const int pw   = p0 + 32 * wv;             // this wave's 32-px base

    const float* fcam = feat  + (size_t)bn * CCH * HWF;
    const float* dcam = depth + (size_t)bn * DDE * HWF;

    // ---- issue ALL 16 independent loads up front (consumed in issue order below)
    float4 f0[4], f1[4], d0[4], d1[4];
#pragma unroll
    for (int i = 0; i < 4; ++i)
        f0[i] = *(const float4*)(fcam + (size_t)(16*i + lh) * HWF + pw + 4*lq);
#pragma unroll
    for (int i = 0; i < 4; ++i)
        f1[i] = *(const float4*)(fcam + (size_t)(16*i + lh) * HWF + pw + 16 + 4*lq);
#pragma unroll
    for (int i = 0; i < 4; ++i)
        d0[i] = *(const float4*)(dcam + (size_t)(lh + 16*i) * HWF + pw + 4*lq);
#pragma unroll
    for (int i = 0; i < 4; ++i)
        d1[i] = *(const float4*)(dcam + (size_t)(lh + 16*i) * HWF + pw + 16 + 4*lq);

    float* ocam = feat_t + (size_t)bn * HWF * CCH;

    // ---- subtile 0: LDS transpose write, read back, coalesced store
#pragma unroll
    for (int i = 0; i < 4; ++i) {
        tile[wv][4*lq + 0][16*i + lh] = f0[i].x;
        tile[wv][4*lq + 1][16*i + lh] = f0[i].y;
        tile[wv][4*lq + 2][16*i + lh] = f0[i].z;
        tile[wv][4*lq + 3][16*i + lh] = f0[i].w;
    }
#pragma unroll
    for (int r = 0; r < 4; ++r) {
        float4 o = *(const float4*)(&tile[wv][lh][16*r + 4*lq]);
        *(float4*)(ocam + (size_t)(pw + lh) * CCH + 16*r + 4*lq) = o;
    }

    // ---- subtile 1: reuse the same tile (same-wave WAR; DS ops in-order per wave)
#pragma unroll
    for (int i = 0; i < 4; ++i) {
        tile[wv][4*lq + 0][16*i + lh] = f1[i].x;
        tile[wv][4*lq + 1][16*i + lh] = f1[i].y;
        tile[wv][4*lq + 2][16*i + lh] = f1[i].z;
        tile[wv][4*lq + 3][16*i + lh] = f1[i].w;
    }
#pragma unroll
    for (int r = 0; r < 4; ++r) {
        float4 o = *(const float4*)(&tile[wv][lh][16*r + 4*lq]);
        *(float4*)(ocam + (size_t)(pw + 16 + lh) * CCH + 16*r + 4*lq) = o;
    }

    // ---- conf: per-lane 4-plane max, then reduce over the 16 lanes sharing lq
    float4 m0 = f4max(f4max(d0[0], d0[1]), f4max(d0[2], d0[3]));
    float4 m1 = f4max(f4max(d1[0], d1[1]), f4max(d1[2], d1[3]));
#pragma unroll
    for (int m = 4; m <= 32; m <<= 1) {
        m0.x = fmaxf(m0.x, __shfl_xor(m0.x, m));
        m0.y = fmaxf(m0.y, __shfl_xor(m0.y, m));
        m0.z = fmaxf(m0.z, __shfl_xor(m0.z, m));
        m0.w = fmaxf(m0.w, __shfl_xor(m0.w, m));
        m1.x = fmaxf(m1.x, __shfl_xor(m1.x, m));
        m1.y = fmaxf(m1.y, __shfl_xor(m1.y, m));
        m1.z = fmaxf(m1.z, __shfl_xor(m1.z, m));
        m1.w = fmaxf(m1.w, __shfl_xor(m1.w, m));
    }
    if (lh == 0) {
        *(float4*)(conf + (size_t)bn * HWF + pw + 4*lq)      = m0;
        *(float4*)(conf + (size_t)bn * HWF + pw + 16 + 4*lq) = m1;
    }

    // ---- histogram: each wave, its own 32 px on lanes 0..31 (c00 bin only)
    {
        Geo g = geo_compute(bn, pw + (lane & 31), I_inv, E_inv, Vm);
        const int base = (bn / NN) * HWB;
        const int cell = ((lane < 32) && g.valid) ? base + g.c00 : -1;
        bool leader; int runlen, leadlane;
        run_info(cell, lane, leader, runlen, leadlane);
        if (leader) atomicAdd(&counts[cell], runlen);
    }
}

// D1: per-256-block exclusive scan of counts
__global__ __launch_bounds__(256) void scan1_kernel(
    const int* __restrict__ counts, int* __restrict__ offsets, int* __restrict__ bsum)
{
    __shared__ int tmp[256];
    const int t = threadIdx.x;
    const int i = blockIdx.x * 256 + t;
    int v = counts[i];
    tmp[t] = v; __syncthreads();
    for (int off = 1; off < 256; off <<= 1) {
        int x = (t >= off) ? tmp[t - off] : 0;
        __syncthreads();
        tmp[t] += x;
        __syncthreads();
    }
    offsets[i] = tmp[t] - v;
    if (t == 255) bsum[blockIdx.x] = tmp[255];
}

// D2+D3 merged: each block sums preceding block-sums itself, finalizes offsets+cursor.
__global__ __launch_bounds__(256) void scan3_kernel(
    int* __restrict__ offsets, const int* __restrict__ bsum, int* __restrict__ cursor)
{
    __shared__ int s[256];
    const int t = threadIdx.x;
    int part = 0;
    for (int i = t; i < blockIdx.x; i += 256) part += bsum[i];
    s[t] = part; __syncthreads();
    for (int off = 128; off > 0; off >>= 1) {
        if (t < off) s[t] += s[t + off];
        __syncthreads();
    }
    const int i = blockIdx.x * 256 + t;
    int v = offsets[i] + s[0];
    offsets[i] = v;
    cursor[i]  = v;
}

// E: place ONE entry per valid pixel: uint4{bin(c00), pixel, w00|w10, w01|w11}
//    weights (x conf) packed u16 fixed-point (err <= 8e-6, far below fp32 tolerance).
__global__ __launch_bounds__(256) void place_kernel(
    const float* __restrict__ conf,
    const float* __restrict__ I_inv, const float* __restrict__ E_inv,
    const float* __restrict__ Vm,
    int* __restrict__ cursor, uint4* __restrict__ entries)
{
    const int bn = blockIdx.y;
    const int p  = blockIdx.x * blockDim.x + threadIdx.x;
    const int lane = threadIdx.x & 63;
    const int inb = (p < HWF);
    const int pp = inb ? p : HWF - 1;
    Geo g = geo_compute(bn, pp, I_inv, E_inv, Vm);
    const int valid = inb && g.valid;
    if (__ballot(valid) == 0ull) return;
    const int base = (bn / NN) * HWB;
    const int bin  = valid ? base + g.c00 : -1;

    bool leader; int runlen, leadlane;
    run_info(bin, lane, leader, runlen, leadlane);
    int pos_leader = 0;
    if (leader) pos_leader = atomicAdd(&cursor[bin], runlen);
    int pos = __shfl(pos_leader, leadlane) + (lane - leadlane);
    if (valid) {
        const float cf = conf[(size_t)bn * HWF + pp];
        entries[pos] = make_uint4((unsigned)bin, (unsigned)(bn * HWF + pp),
                                  pack2w(g.w00 * cf, g.w10 * cf),
                                  pack2w(g.w01 * cf, g.w11 * cf));
    }
}

// F: segmented gather, one wave per 64-entry chunk, lane = channel.
//    One feat_t row read per PIXEL (not per corner); 4 register accumulators per run;
//    4 atomics per run end to bin + {0,1,200,201}.
__global__ __launch_bounds__(256) void gather_seg_kernel(
    const uint4* __restrict__ entries, const int* __restrict__ total_ptr,
    const float* __restrict__ feat_t, float* __restrict__ acc)
{
    const int lane = threadIdx.x & 63, wv = threadIdx.x >> 6;
    const int chunk = blockIdx.x * 4 + wv;
    const int total = *total_ptr;
    const int start = chunk * 64;
    if (start >= total) return;
    const int m = min(64, total - start);

    int myb = -1;
    uint4 mye = make_uint4(0u, 0u, 0u, 0u);
    if (lane < m) { mye = entries[start + lane]; myb = (int)mye.x; }

    const float inv = 1.0f / 65535.0f;
    float a00 = 0.f, a10 = 0.f, a01 = 0.f, a11 = 0.f;
    for (int j = 0; j < 64; j += 8) {
        int bb[9]; unsigned px[8], wA[8], wB[8];
#pragma unroll
        for (int k = 0; k < 8; ++k) {
            bb[k] = __shfl(myb, j + k);
            px[k] = (unsigned)__shfl((int)mye.y, j + k);
            wA[k] = (unsigned)__shfl((int)mye.z, j + k);
            wB[k] = (unsigned)__shfl((int)mye.w, j + k);
        }
        bb[8] = (j + 8 < 64) ? __shfl(myb, j + 8) : -2;
        float f[8];
#pragma unroll
        for (int k = 0; k < 8; ++k)
            f[k] = (bb[k] >= 0) ? feat_t[(size_t)px[k] * CCH + lane] : 0.0f;
#pragma unroll
        for (int k = 0; k < 8; ++k) {
            a00 = fmaf(f[k], (float)(wA[k] & 0xffffu) * inv, a00);
            a10 = fmaf(f[k], (float)(wA[k] >> 16)     * inv, a10);
            a01 = fmaf(f[k], (float)(wB[k] & 0xffffu) * inv, a01);
            a11 = fmaf(f[k], (float)(wB[k] >> 16)     * inv, a11);
            if (bb[k] != bb[k + 1]) {
                if (bb[k] >= 0) {
                    float* ab = acc + (size_t)bb[k] * CCH + lane;
                    atomicAdd(ab,                       a00);
                    atomicAdd(ab + (size_t)1   * CCH,   a10);
                    atomicAdd(ab + (size_t)200 * CCH,   a01);
                    atomicAdd(ab + (size_t)201 * CCH,   a11);
                }
                a00 = a10 = a01 = a11 = 0.f;
            }
        }
    }
}

// G: out[b][c][cell] = acc[b*HWB+cell][c] / 6 -- float4 both sides via LDS tile
__global__ __launch_bounds__(256) void finalize_kernel(
    const float* __restrict__ acc, float* __restrict__ out)
{
    __shared__ float t[64][66];
    const int b     = blockIdx.y;
    const int cell0 = blockIdx.x * 64;
    const int cc    = threadIdx.x >> 2;   // read: cell row / write: channel
    const int q     = threadIdx.x & 3;

    const float* abase = acc + ((size_t)b * HWB + cell0) * CCH;
#pragma unroll
    for (int i = 0; i < 4; ++i) {
        const int cg = q + 4 * i;
        float4 f = *(const float4*)(abase + (size_t)cc * CCH + 4 * cg);
        t[cc][4*cg+0] = f.x; t[cc][4*cg+1] = f.y;
        t[cc][4*cg+2] = f.z; t[cc][4*cg+3] = f.w;
    }
    __syncthreads();
    float* obase = out + (size_t)b * CCH * HWB + cell0;
#pragma unroll
    for (int i = 0; i < 4; ++i) {
        const int lg = q + 4 * i;           // cell-group
        float4 o;
        o.x = t[4*lg+0][cc] * (1.0f/6.0f);
        o.y = t[4*lg+1][cc] * (1.0f/6.0f);
        o.z = t[4*lg+2][cc] * (1.0f/6.0f);
        o.w = t[4*lg+3][cc] * (1.0f/6.0f);
        *(float4*)(obase + (size_t)cc * HWB + 4 * lg) = o;
    }
}

// ---------------- fallback (round-4 atomic splat) if ws too small ----------------
__global__ __launch_bounds__(256) void splat_kernel(
    const float* __restrict__ feat, const float* __restrict__ depth,
    const float* __restrict__ I_inv, const float* __restrict__ E_inv,
    const float* __restrict__ Vm, float* __restrict__ acc)
{
    __shared__ float fshare[64][65];
    __shared__ float cpart2[4][64];
    const int bn = blockIdx.y, b = bn / NN, p0 = blockIdx.x * 64;
    const int lane = threadIdx.x & 63, wv = threadIdx.x >> 6;
    const float* fbase = feat + (size_t)bn * CCH * HWF + p0;
#pragma unroll
    for (int c = wv; c < CCH; c += 4)
        fshare[lane][c] = fbase[(size_t)c * HWF + lane];
    const float* dbase = depth + (size_t)bn * DDE * HWF + p0;
    float m = dbase[(size_t)(wv * 16) * HWF + lane];
#pragma unroll
    for (int d = wv * 16 + 1; d < wv * 16 + 16; ++d)
        m = fmaxf(m, dbase[(size_t)d * HWF + lane]);
    cpart2[wv][lane] = m;
    __syncthreads();
    float* ab = acc + ((size_t)b * HWB) * CCH + lane;
    for (int s = wv * 16; s < wv * 16 + 16; ++s) {
        Geo g = geo_compute(bn, p0 + s, I_inv, E_inv, Vm);
        if (!g.valid) continue;
        float cf = fmaxf(fmaxf(cpart2[0][s], cpart2[1][s]), fmaxf(cpart2[2][s], cpart2[3][s]));
        float f = fshare[s][lane];
        atomicAdd(ab + (size_t)g.c00 * CCH, f * (g.w00 * cf));
        atomicAdd(ab + (size_t)g.c10 * CCH, f * (g.w10 * cf));
        atomicAdd(ab + (size_t)g.c01 * CCH, f * (g.w01 * cf));
        atomicAdd(ab + (size_t)g.c11 * CCH, f * (g.w11 * cf));
    }
}

extern "C" void kernel_launch(void* const* d_in, const int* in_sizes, int n_in,
                              void* d_out, int out_size, void* d_ws, size_t ws_size,
                              hipStream_t stream) {
    const float* feat  = (const float*)d_in[0];
    const float* depth = (const float*)d_in[1];
    const float* I_inv = (const float*)d_in[2];
    const float* E_inv = (const float*)d_in[3];
    const float* Vm    = (const float*)d_in[4];
    float* out = (float*)d_out;

    size_t off = 0;
    char* wsb = (char*)d_ws;
    auto carve = [&](size_t bytes) -> void* {
        void* p = wsb + off; off += (bytes + 255) & ~(size_t)255; return p;
    };
    // acc and counts adjacent -> single memset (acc bytes are 256B-multiple)
    float* feat_t  = (float*)carve((size_t)BB * NN * CCH * HWF * 4);  // 68.8 MB
    float* acc     = (float*)carve(ACC_ELEMS * 4);                    // 20.5 MB
    int*   counts  = (int*)  carve((NBINS_PAD + 256) * 4);            // 0.33 MB
    uint4* entries = (uint4*)carve((size_t)MAXENT1 * 16);             //  4.3 MB
    float* conf    = (float*)carve((size_t)BB * NN * HWF * 4);        //  1.1 MB
    int*   offsets = (int*)  carve((NBINS_PAD + 256) * 4);
    int*   cursor  = (int*)  carve((NBINS_PAD + 256) * 4);
    int*   bsum    = (int*)  carve(NSCANB * 4);

    if (off <= ws_size) {
        hipMemsetAsync(acc, 0, ACC_ELEMS * 4 + (NBINS_PAD + 256) * 4, stream);

        dim3 pgrid(HWF / 128, BB * NN);                // (175,12)
        prep_kernel<<<pgrid, 256, 0, stream>>>(feat, depth, I_inv, E_inv, Vm,
                                               feat_t, conf, counts);

        scan1_kernel<<<NSCANB, 256, 0, stream>>>(counts, offsets, bsum);
        scan3_kernel<<<NSCANB, 256, 0, stream>>>(offsets, bsum, cursor);

        dim3 plgrid((HWF + 255) / 256, BB * NN);       // (88,12)
        place_kernel<<<plgrid, 256, 0, stream>>>(conf, I_inv, E_inv, Vm,
                                                 cursor, entries);

        gather_seg_kernel<<<NCHUNK1 / 4, 256, 0, stream>>>(
            entries, offsets + NBINS, feat_t, acc);

        dim3 fgrid(HWB / 64, BB);                      // (625,2)
        finalize_kernel<<<fgrid, 256, 0, stream>>>(acc, out);
    } else {
        float* acc0 = (float*)d_ws;
        hipMemsetAsync(acc0, 0, ACC_ELEMS * 4, stream);
        dim3 grid(HWF / 64, BB * NN);
        splat_kernel<<<grid, 256, 0, stream>>>(feat, depth, I_inv, E_inv, Vm, acc0);
        dim3 fgrid(HWB / 64, BB);
        finalize_kernel<<<fgrid, 256, 0, stream>>>(acc0, out);
    }
}